// Round 4
// baseline (331.193 us; speedup 1.0000x reference)
//
#include <hip/hip_runtime.h>
#include <math.h>

// ManipulabilityCost: per 6x7 fp32 J: S = J*J^T, score = sqrt(det S),
// NaN->0, clamp 0.1, cost = w*(0.1-score)/0.1.
//
// NUMERICS — replicate numpy's fp32 pipeline BITWISE. Near-singular matrices
// (lambda_min ~ 5e-6) amplify single-ulp differences in S or LU intermediates
// to O(10%) det changes, so the exact rounding sequence matters everywhere.
//
//   1) Gram = np.einsum (numpy 2.x npyv path, x86-64 baseline SSE3, vstep=4):
//      count=7 -> one SIMD muladd into zero accum (exact products p0..p3),
//      npyv_sum_f32 via SSE3 hadd: (p0+p1)+(p2+p3), then scalar ascending
//      tail +p4 +p5 +p6, no FMA (SSE3 has none).            [CHANGED vs R3]
//   2) det LU = OpenBLAS getf2_k (sgetrf n=6 -> single getf2 call):
//      iamax strict-> first max; full-row swap; temp2 = 1/pivot ALWAYS;
//      scal = l*temp2; ger alpha=-1: t = -u, a = fmaf(l, t, a) (Zen/Haswell
//      FMA kernels).                                          [same as R3]
//   3) numpy umath_linalg det epilogue: det = sign*expf(sum logf(|d_i|)),
//      fp32, sign = ipiv parity XOR negative diagonals.       [same as R3]
//   4) epilogue fp32 throughout (NEP50 weak scalars).         [same as R3]
//
// PERF: memory-bound — 176 MB in / 4 MB out => ~29 us floor at 6.3 TB/s.
// LDS-staged coalesced loads (pad 43: odd stride => only 2-way bank alias, free).

constexpr int MAT = 42;   // 6*7 floats per matrix
constexpr int PAD = 43;
constexpr int BLK = 256;  // threads per block == matrices per block

__global__ __launch_bounds__(BLK) void manip_cost_kernel(
    const float* __restrict__ jac, const float* __restrict__ wptr,
    float* __restrict__ out, int n)
{
    __shared__ float sm[BLK * PAD];  // 43 KB -> ~3 blocks/CU
    const int tid = threadIdx.x;
    const long long base  = (long long)blockIdx.x * BLK;
    const long long gbase = base * MAT;
    const long long total = (long long)n * MAT;

    // Stage: 42 perfectly-coalesced dword loads, scattered into padded LDS rows.
    #pragma unroll
    for (int k = 0; k < MAT; ++k) {
        long long gidx = gbase + (long long)k * BLK + tid;
        if (gidx < total) {
            int i   = k * BLK + tid;
            int row = i / MAT;
            int col = i - row * MAT;
            sm[row * PAD + col] = jac[gidx];
        }
    }
    __syncthreads();

    const long long m = base + tid;
    if (m >= n) return;

    float J[MAT];
    #pragma unroll
    for (int j = 0; j < MAT; ++j) J[j] = sm[tid * PAD + j];

    // S = J J^T, numpy-2.x einsum npyv/SSE3 rounding sequence (see header).
    float A[6][6];
    #pragma unroll
    for (int i = 0; i < 6; ++i) {
        #pragma unroll
        for (int k = 0; k <= i; ++k) {
            float p[7];
            #pragma unroll
            for (int j = 0; j < 7; ++j)
                p[j] = __fmul_rn(J[i * 7 + j], J[k * 7 + j]);
            float s = __fadd_rn(__fadd_rn(p[0], p[1]), __fadd_rn(p[2], p[3]));
            s = __fadd_rn(s, p[4]);
            s = __fadd_rn(s, p[5]);
            s = __fadd_rn(s, p[6]);
            A[i][k] = s;
            A[k][i] = s;   // einsum computes (k,i) identically -> bitwise symmetric
        }
    }

    // OpenBLAS getf2_k replica (fp32). Row/col-major moot: S bitwise symmetric.
    int neg = 0;
    #pragma unroll
    for (int j = 0; j < 6; ++j) {
        // isamax over column j, rows j..5: strict >, first max wins.
        int p = j;
        float amax = fabsf(A[j][j]);
        #pragma unroll
        for (int r = j + 1; r < 6; ++r) {
            float v = fabsf(A[r][j]);
            if (v > amax) { amax = v; p = r; }
        }
        neg ^= (p != j);
        // Predicated full-row swap j<->p (unrolled: no dynamic reg indexing).
        #pragma unroll
        for (int r = j + 1; r < 6; ++r) {
            bool sw = (p == r);
            #pragma unroll
            for (int c = 0; c < 6; ++c) {
                float tj = A[j][c], tr = A[r][c];
                A[j][c] = sw ? tr : tj;
                A[r][c] = sw ? tj : tr;
            }
        }
        float piv = A[j][j];
        if (piv != 0.0f) {
            float rcp = 1.0f / piv;          // getf2_k: reciprocal ALWAYS
            #pragma unroll
            for (int i = j + 1; i < 6; ++i)
                A[i][j] = __fmul_rn(A[i][j], rcp);
            // ger, alpha = -1: t = -u[jj] (exact), a = fmaf(l, t, a).
            #pragma unroll
            for (int jj = j + 1; jj < 6; ++jj) {
                float t = -A[j][jj];
                #pragma unroll
                for (int i = j + 1; i < 6; ++i)
                    A[i][jj] = fmaf(A[i][j], t, A[i][jj]);
            }
        }
    }

    // numpy det epilogue: det = sign * expf(sum logf(|d_i|)), fp32, i = 0..5.
    float sign = neg ? -1.0f : 1.0f;
    float logdet = 0.0f;
    #pragma unroll
    for (int i = 0; i < 6; ++i) {
        float d = A[i][i];
        if (d < 0.0f) { sign = -sign; d = -d; }
        logdet = __fadd_rn(logdet, logf(d));   // d==0 -> -inf -> det = +/-0
    }
    float det = __fmul_rn(sign, expf(logdet));

    float score = sqrtf(det);            // det<0 -> NaN
    if (!(score == score)) score = 0.0f; // NaN -> 0
    score = fminf(score, 0.1f);
    float r = __fdiv_rn(__fsub_rn(0.1f, score), 0.1f);  // fp32 throughout
    out[m] = __fmul_rn(wptr[0], r);
}

extern "C" void kernel_launch(void* const* d_in, const int* in_sizes, int n_in,
                              void* d_out, int out_size, void* d_ws, size_t ws_size,
                              hipStream_t stream) {
    const float* jac = (const float*)d_in[0];
    const float* w   = (const float*)d_in[1];
    float* out       = (float*)d_out;
    int n    = in_sizes[0] / MAT;
    int grid = (n + BLK - 1) / BLK;
    manip_cost_kernel<<<grid, BLK, 0, stream>>>(jac, w, out, n);
}

// Round 5
// 241.080 us; speedup vs baseline: 1.3738x; 1.3738x over previous
//
#include <hip/hip_runtime.h>
#include <math.h>

// ManipulabilityCost: per 6x7 fp32 J: S = J*J^T, score = sqrt(det S),
// NaN->0, clamp 0.1, cost = w*(0.1-score)/0.1.
//
// NUMERICS (LOCKED — R4 passed, absmax 1.5/1.68; every arithmetic op below is
// byte-identical to R4; only data movement changed):
//   1) Gram = numpy-2.x einsum npyv/SSE3: products p0..p6, (p0+p1)+(p2+p3),
//      then +p4 +p5 +p6, no FMA.
//   2) det LU = OpenBLAS getf2_k: iamax strict->, full row swap, reciprocal-
//      multiply always, ger a = fmaf(l, -u, a).
//   3) det epilogue = sign * expf(sum logf(|d_i|)), fp32.
//   4) cost epilogue fp32 throughout.
//
// PERF (R4 post-mortem): 159 us, VALUBusy 16.7%, hbm 7% — latency-bound.
// VGPR=68 => compiler serialized staging into 42 x (load; vmcnt(0); ds_write)
// ~900-cyc round trips per block. Fix: async direct-to-LDS DMA
// (__builtin_amdgcn_global_load_lds, width=16). Block input is contiguous, so
// the wave-uniform-base + lane*16 layout works with an UNPADDED LDS buffer
// (stride-42 reads: 4-way bank alias = 1.58x issue, negligible). BLK=128 =>
// 21504 B = exactly 21 x 1024 B chunks, 7 blocks/CU resident for deep
// block-level pipelining of DMA latency.

constexpr int MAT = 42;   // 6*7 floats per matrix
constexpr int BLK = 128;  // matrices per block; 128*42*4 = 21504 B = 21 chunks
constexpr int CHUNKS = BLK * MAT * 4 / 1024;  // 21 x (64 lanes x 16 B)

typedef const __attribute__((address_space(1))) void g_void;
typedef __attribute__((address_space(3))) void l_void;

__global__ __launch_bounds__(BLK) void manip_cost_kernel(
    const float* __restrict__ jac, const float* __restrict__ wptr,
    float* __restrict__ out, int n)
{
    __shared__ float sm[BLK * MAT];  // unpadded: DMA lands lane*16 contiguous
    const int tid  = threadIdx.x;
    const int wave = tid >> 6;
    const int lane = tid & 63;
    const long long base  = (long long)blockIdx.x * BLK;
    const long long gbase = base * MAT;

    if (base + BLK <= (long long)n) {
        // Fast path: async DMA, all chunks in flight, one vmcnt drain at barrier.
        const float* gsrc = jac + gbase;
        #pragma unroll
        for (int c = wave; c < CHUNKS; c += BLK / 64) {
            const float* g = gsrc + c * 256 + lane * 4;  // lane*16 B
            float*       l = sm + c * 256;               // wave-uniform base
            __builtin_amdgcn_global_load_lds((g_void*)g, (l_void*)l, 16, 0, 0);
        }
    } else {
        // Tail path (never taken at n = 1M = 8192*128; kept for generality).
        const long long total = (long long)n * MAT;
        #pragma unroll
        for (int k = 0; k < MAT; ++k) {
            long long gidx = gbase + (long long)k * BLK + tid;
            if (gidx < total) sm[k * BLK + tid] = jac[gidx];
        }
    }
    __syncthreads();  // compiler emits s_waitcnt vmcnt(0) before s_barrier

    const long long m = base + tid;
    if (m >= n) return;

    float J[MAT];
    #pragma unroll
    for (int j = 0; j < MAT; ++j) J[j] = sm[tid * MAT + j];

    // S = J J^T, numpy-2.x einsum npyv/SSE3 rounding sequence. [LOCKED]
    float A[6][6];
    #pragma unroll
    for (int i = 0; i < 6; ++i) {
        #pragma unroll
        for (int k = 0; k <= i; ++k) {
            float p[7];
            #pragma unroll
            for (int j = 0; j < 7; ++j)
                p[j] = __fmul_rn(J[i * 7 + j], J[k * 7 + j]);
            float s = __fadd_rn(__fadd_rn(p[0], p[1]), __fadd_rn(p[2], p[3]));
            s = __fadd_rn(s, p[4]);
            s = __fadd_rn(s, p[5]);
            s = __fadd_rn(s, p[6]);
            A[i][k] = s;
            A[k][i] = s;
        }
    }

    // OpenBLAS getf2_k replica (fp32). [LOCKED]
    int neg = 0;
    #pragma unroll
    for (int j = 0; j < 6; ++j) {
        int p = j;
        float amax = fabsf(A[j][j]);
        #pragma unroll
        for (int r = j + 1; r < 6; ++r) {
            float v = fabsf(A[r][j]);
            if (v > amax) { amax = v; p = r; }
        }
        neg ^= (p != j);
        #pragma unroll
        for (int r = j + 1; r < 6; ++r) {
            bool sw = (p == r);
            #pragma unroll
            for (int c = 0; c < 6; ++c) {
                float tj = A[j][c], tr = A[r][c];
                A[j][c] = sw ? tr : tj;
                A[r][c] = sw ? tj : tr;
            }
        }
        float piv = A[j][j];
        if (piv != 0.0f) {
            float rcp = 1.0f / piv;
            #pragma unroll
            for (int i = j + 1; i < 6; ++i)
                A[i][j] = __fmul_rn(A[i][j], rcp);
            #pragma unroll
            for (int jj = j + 1; jj < 6; ++jj) {
                float t = -A[j][jj];
                #pragma unroll
                for (int i = j + 1; i < 6; ++i)
                    A[i][jj] = fmaf(A[i][j], t, A[i][jj]);
            }
        }
    }

    // numpy det epilogue: det = sign * expf(sum logf(|d_i|)), fp32. [LOCKED]
    float sign = neg ? -1.0f : 1.0f;
    float logdet = 0.0f;
    #pragma unroll
    for (int i = 0; i < 6; ++i) {
        float d = A[i][i];
        if (d < 0.0f) { sign = -sign; d = -d; }
        logdet = __fadd_rn(logdet, logf(d));
    }
    float det = __fmul_rn(sign, expf(logdet));

    float score = sqrtf(det);
    if (!(score == score)) score = 0.0f;
    score = fminf(score, 0.1f);
    float r = __fdiv_rn(__fsub_rn(0.1f, score), 0.1f);
    out[m] = __fmul_rn(wptr[0], r);
}

extern "C" void kernel_launch(void* const* d_in, const int* in_sizes, int n_in,
                              void* d_out, int out_size, void* d_ws, size_t ws_size,
                              hipStream_t stream) {
    const float* jac = (const float*)d_in[0];
    const float* w   = (const float*)d_in[1];
    float* out       = (float*)d_out;
    int n    = in_sizes[0] / MAT;
    int grid = (n + BLK - 1) / BLK;
    manip_cost_kernel<<<grid, BLK, 0, stream>>>(jac, w, out, n);
}

// Round 7
// 240.034 us; speedup vs baseline: 1.3798x; 1.0044x over previous
//
#include <hip/hip_runtime.h>
#include <math.h>

// ManipulabilityCost: per 6x7 fp32 J: S = J*J^T, score = sqrt(det S),
// NaN->0, clamp 0.1, cost = w*(0.1-score)/0.1.
//
// NUMERICS (LOCKED — passed R4/R5, absmax 1.5/1.68; arithmetic is
// byte-identical; only data movement differs):
//   1) Gram = numpy-2.x einsum npyv/SSE3: products p0..p6, (p0+p1)+(p2+p3),
//      then +p4 +p5 +p6, no FMA.
//   2) det LU = OpenBLAS getf2_k: iamax strict->, full row swap (restricted
//      to live columns c>=j — dead L-storage below-diag never re-read),
//      reciprocal-multiply always, ger a = fmaf(l, -u, a).
//   3) det epilogue = sign * expf(sum logf(|d_i|)), fp32.
//   4) cost epilogue fp32 throughout.
//
// PERF history: R4 159us (scalar staging) -> R5 ~69us (DMA 16B, BLK=128).
// R6 FAILED (absmax 100): width=12 global_load_lds scrambles LDS — its lane
// stride is NOT 12 (only width 4 => lane*4 and 16 => lane*16 are HW-verified:
// learn_hip m03/m97). R7 = R6 structure with verified widths only:
// 10752 B/block = 10 x 1024 B (width 16) + 2 x 256 B (width 4).
// BLK=64: single-wave blocks, ~15 blocks/CU (LDS-limited) for fine-grained
// DMA latency hiding; J read as 21 x ds_read_b64.

constexpr int MAT = 42;   // 6*7 floats per matrix
constexpr int BLK = 64;   // one wave per block; 64*42*4 = 10752 B LDS

typedef const __attribute__((address_space(1))) void g_void;
typedef __attribute__((address_space(3))) void l_void;

__global__ __launch_bounds__(BLK, 4) void manip_cost_kernel(
    const float* __restrict__ jac, const float* __restrict__ wptr,
    float* __restrict__ out, int n)
{
    __shared__ float sm[BLK * MAT];  // unpadded: DMA layout is exact-contiguous
    const int tid = threadIdx.x;     // == lane (single wave)
    const long long base  = (long long)blockIdx.x * BLK;
    const long long gbase = base * MAT;

    if (base + BLK <= (long long)n) {
        const float* gsrc = jac + gbase;
        // 10 x 1024-B chunks, width=16 (lane*16 LDS stride — m97-verified).
        #pragma unroll
        for (int c = 0; c < 10; ++c) {
            const float* g = gsrc + c * 256 + tid * 4;   // lane*16 B
            float*       l = sm + c * 256;               // wave-uniform base
            __builtin_amdgcn_global_load_lds((g_void*)g, (l_void*)l, 16, 0, 0);
        }
        // tail 512 B: 2 x 256-B chunks, width=4 (lane*4 — m03-verified).
        #pragma unroll
        for (int c = 0; c < 2; ++c) {
            const float* g = gsrc + 2560 + c * 64 + tid;
            float*       l = sm + 2560 + c * 64;
            __builtin_amdgcn_global_load_lds((g_void*)g, (l_void*)l, 4, 0, 0);
        }
    } else {
        // Tail path (n = 1M = 16384*64 exactly; kept for generality).
        const long long total = (long long)n * MAT;
        #pragma unroll
        for (int k = 0; k < MAT; ++k) {
            long long gidx = gbase + (long long)k * BLK + tid;
            if (gidx < total) sm[k * BLK + tid] = jac[gidx];
        }
    }
    __builtin_amdgcn_s_waitcnt(0);   // explicit vmcnt/lgkm drain (single-wave
    __syncthreads();                 // barrier may be elided by the compiler)

    const long long m = base + tid;
    if (m >= n) return;

    // 21 x ds_read_b64 (tid*168 B, 8-B aligned). Pure loads — no numerics.
    float J[MAT];
    const float2* Jp = (const float2*)(sm + tid * MAT);
    #pragma unroll
    for (int h = 0; h < 21; ++h) {
        float2 v = Jp[h];
        J[2 * h]     = v.x;
        J[2 * h + 1] = v.y;
    }

    // S = J J^T, numpy-2.x einsum npyv/SSE3 rounding sequence. [LOCKED]
    float A[6][6];
    #pragma unroll
    for (int i = 0; i < 6; ++i) {
        #pragma unroll
        for (int k = 0; k <= i; ++k) {
            float p[7];
            #pragma unroll
            for (int j = 0; j < 7; ++j)
                p[j] = __fmul_rn(J[i * 7 + j], J[k * 7 + j]);
            float s = __fadd_rn(__fadd_rn(p[0], p[1]), __fadd_rn(p[2], p[3]));
            s = __fadd_rn(s, p[4]);
            s = __fadd_rn(s, p[5]);
            s = __fadd_rn(s, p[6]);
            A[i][k] = s;
            A[k][i] = s;
        }
    }

    // OpenBLAS getf2_k replica (fp32). [LOCKED — swap narrowed to live cols]
    int neg = 0;
    #pragma unroll
    for (int j = 0; j < 6; ++j) {
        int p = j;
        float amax = fabsf(A[j][j]);
        #pragma unroll
        for (int r = j + 1; r < 6; ++r) {
            float v = fabsf(A[r][j]);
            if (v > amax) { amax = v; p = r; }
        }
        neg ^= (p != j);
        #pragma unroll
        for (int r = j + 1; r < 6; ++r) {
            bool sw = (p == r);
            #pragma unroll
            for (int c = j; c < 6; ++c) {   // c<j entries are dead L-storage
                float tj = A[j][c], tr = A[r][c];
                A[j][c] = sw ? tr : tj;
                A[r][c] = sw ? tj : tr;
            }
        }
        float piv = A[j][j];
        if (piv != 0.0f) {
            float rcp = 1.0f / piv;          // getf2_k: reciprocal ALWAYS
            #pragma unroll
            for (int i = j + 1; i < 6; ++i)
                A[i][j] = __fmul_rn(A[i][j], rcp);
            #pragma unroll
            for (int jj = j + 1; jj < 6; ++jj) {
                float t = -A[j][jj];
                #pragma unroll
                for (int i = j + 1; i < 6; ++i)
                    A[i][jj] = fmaf(A[i][j], t, A[i][jj]);
            }
        }
    }

    // numpy det epilogue: det = sign * expf(sum logf(|d_i|)), fp32. [LOCKED]
    float sign = neg ? -1.0f : 1.0f;
    float logdet = 0.0f;
    #pragma unroll
    for (int i = 0; i < 6; ++i) {
        float d = A[i][i];
        if (d < 0.0f) { sign = -sign; d = -d; }
        logdet = __fadd_rn(logdet, logf(d));
    }
    float det = __fmul_rn(sign, expf(logdet));

    float score = sqrtf(det);
    if (!(score == score)) score = 0.0f;
    score = fminf(score, 0.1f);
    float r = __fdiv_rn(__fsub_rn(0.1f, score), 0.1f);
    out[m] = __fmul_rn(wptr[0], r);
}

extern "C" void kernel_launch(void* const* d_in, const int* in_sizes, int n_in,
                              void* d_out, int out_size, void* d_ws, size_t ws_size,
                              hipStream_t stream) {
    const float* jac = (const float*)d_in[0];
    const float* w   = (const float*)d_in[1];
    float* out       = (float*)d_out;
    int n    = in_sizes[0] / MAT;
    int grid = (n + BLK - 1) / BLK;
    manip_cost_kernel<<<grid, BLK, 0, stream>>>(jac, w, out, n);
}